// Round 11
// baseline (556.907 us; speedup 1.0000x reference)
//
#include <hip/hip_runtime.h>

typedef __attribute__((ext_vector_type(8))) short short8;
typedef __attribute__((ext_vector_type(4))) float f32x4;
typedef unsigned short u16;
typedef unsigned int u32;

#define NH 16

#if __has_builtin(__builtin_amdgcn_exp2f)
#define EXP2(x) __builtin_amdgcn_exp2f(x)
#else
#define EXP2(x) exp2f(x)
#endif

__device__ __forceinline__ u32 f2bf(float f) {
  u32 u = __builtin_bit_cast(u32, f);
  return (u + 0x7fffu + ((u >> 16) & 1u)) >> 16;  // round-nearest-even bf16 bits
}

// v_cvt_pk_bf16_f32: two f32 -> packed bf16x2 (RNE), one instruction.
__device__ __forceinline__ u32 cvtpk(float lo, float hi) {
  u32 r;
  asm("v_cvt_pk_bf16_f32 %0, %1, %2" : "=v"(r) : "v"(lo), "v"(hi));
  return r;
}

// async global->LDS, 16B per lane. LDS dest is wave-uniform base + lane*16.
__device__ __forceinline__ void gload_lds16(const u16* g, u16* l) {
  __builtin_amdgcn_global_load_lds(
      (const __attribute__((address_space(1))) void*)g,
      (__attribute__((address_space(3))) void*)l, 16, 0, 0);
}

// ---------- convert x + Wq,Wk,Wv,Wo (fp32) -> bf16 into ws ----------
__global__ __launch_bounds__(256) void k_convert(
    const float* __restrict__ x, const float* __restrict__ wq,
    const float* __restrict__ wk, const float* __restrict__ wv,
    const float* __restrict__ wo, u16* __restrict__ dst) {
  int i = blockIdx.x * 256 + threadIdx.x;
  size_t e = (size_t)i * 4;
  const float* s; size_t off;
  if (e < 8388608ull)       { s = x;  off = e; }
  else if (e < 9437184ull)  { s = wq; off = e - 8388608ull; }
  else if (e < 10485760ull) { s = wk; off = e - 9437184ull; }
  else if (e < 11534336ull) { s = wv; off = e - 10485760ull; }
  else                      { s = wo; off = e - 11534336ull; }
  float4 d = *(const float4*)(s + off);
  uint2 o;
  o.x = cvtpk(d.x, d.y);
  o.y = cvtpk(d.z, d.w);
  *(uint2*)(dst + e) = o;
}

// ---------- parameterized 8-wave GEMM core (T3+T4): C = A * B^T ----------
// (R8-verified) 512 threads = 8 waves. BM = MT*32, BN = NT*64, BK = 64.
// True dbuf LDS; gload_lds16 staging with constant-per-lane granule XOR
// swizzle; T4 counted vmcnt (never drains to 0 in-loop); raw s_barrier only.
#define GPHASE(MH, NH_, LA, LB)                                                \
  if (LA) {                                                                    \
    _Pragma("unroll")                                                          \
    for (int mt = 0; mt < 4; ++mt)                                             \
      _Pragma("unroll")                                                        \
      for (int ks = 0; ks < 2; ++ks)                                           \
        af[mt][ks] = *(const short8*)(Ab +                                     \
            (wr * MT * 16 + ((MH) * 4 + mt) * 16 + l16) * 64 +                 \
            ((ks * 4 + quad) ^ swz) * 8);                                      \
  }                                                                            \
  if (LB) {                                                                    \
    _Pragma("unroll")                                                          \
    for (int nt = 0; nt < NH2; ++nt)                                           \
      _Pragma("unroll")                                                        \
      for (int ks = 0; ks < 2; ++ks)                                           \
        bfr[nt][ks] = *(const short8*)(Bb +                                    \
            (wn * NT * 16 + ((NH_) * NH2 + nt) * 16 + l16) * 64 +              \
            ((ks * 4 + quad) ^ swz) * 8);                                      \
  }                                                                            \
  __builtin_amdgcn_s_barrier();                                                \
  __builtin_amdgcn_s_setprio(1);                                               \
  _Pragma("unroll")                                                            \
  for (int mt = 0; mt < 4; ++mt)                                               \
    _Pragma("unroll")                                                          \
    for (int nt = 0; nt < NH2; ++nt)                                           \
      _Pragma("unroll")                                                        \
      for (int ks = 0; ks < 2; ++ks)                                           \
        acc[(MH) * 4 + mt][(NH_) * NH2 + nt] =                                 \
            __builtin_amdgcn_mfma_f32_16x16x32_bf16(                           \
                af[mt][ks], bfr[nt][ks], acc[(MH) * 4 + mt][(NH_) * NH2 + nt], \
                0, 0, 0);                                                      \
  __builtin_amdgcn_s_setprio(0);                                               \
  __builtin_amdgcn_s_barrier();                                                \
  __builtin_amdgcn_sched_barrier(0);

#define STAGE_T(T, PB)                                                         \
  {                                                                            \
    const u16* aT = aTh + (T) * 64;                                            \
    const u16* bT = bTh + (T) * 64;                                            \
    u16* aD = &As[PB][0] + dbase;                                              \
    u16* bD = &Bs[PB][0] + dbase;                                              \
    _Pragma("unroll")                                                          \
    for (int j = 0; j < NLA; ++j) gload_lds16(aT + j * 65536, aD + j * 4096);  \
    _Pragma("unroll")                                                          \
    for (int j = 0; j < NLB; ++j) gload_lds16(bT + j * 65536, bD + j * 4096);  \
  }

template <int MT, int NT>
__device__ __forceinline__ void gemm_core(const u16* __restrict__ Aptr,
                                          const u16* __restrict__ Bptr,
                                          int m0, int n0,
                                          f32x4 (&acc)[MT][NT]) {
  constexpr int NLA = MT / 2;   // A gload_lds per thread per K-tile
  constexpr int NLB = NT;       // B gload_lds per thread per K-tile
  constexpr int NLD = NLA + NLB;
  constexpr int NH2 = NT / 2;
  __shared__ u16 As[2][MT * 32 * 64];
  __shared__ u16 Bs[2][NT * 64 * 64];
  const int tid = threadIdx.x;
  const int wave = tid >> 6, lane = tid & 63;
  const int quad = lane >> 4, l16 = lane & 15;
  const int wr = wave >> 2, wn = wave & 3;
  const int swz = l16 & 7;
  const int srow = tid >> 3;
  const int srcg = (tid & 7) ^ (srow & 7);
  const u16* aTh = Aptr + (size_t)(m0 + srow) * 1024 + srcg * 8;
  const u16* bTh = Bptr + (size_t)(n0 + srow) * 1024 + srcg * 8;
  const int dbase = wave * 512;

  {
    f32x4 z = {0.f, 0.f, 0.f, 0.f};
    #pragma unroll
    for (int a = 0; a < MT; ++a)
      #pragma unroll
      for (int b2 = 0; b2 < NT; ++b2) acc[a][b2] = z;
  }

  STAGE_T(0, 0)

  short8 af[4][2], bfr[NH2][2];
  for (int t = 0; t < 16; ++t) {
    const int p = t & 1;
    if (t < 15) {
      STAGE_T(t + 1, p ^ 1)
      if constexpr (NLD == 8)
        asm volatile("s_waitcnt vmcnt(8)" ::: "memory");
      else if constexpr (NLD == 6)
        asm volatile("s_waitcnt vmcnt(6)" ::: "memory");
      else if constexpr (NLD == 4)
        asm volatile("s_waitcnt vmcnt(4)" ::: "memory");
      else
        asm volatile("s_waitcnt vmcnt(0)" ::: "memory");
    } else {
      asm volatile("s_waitcnt vmcnt(0)" ::: "memory");
    }
    __builtin_amdgcn_s_barrier();
    __builtin_amdgcn_sched_barrier(0);
    const u16* Ab = &As[p][0];
    const u16* Bb = &Bs[p][0];
    if constexpr (MT == 8) {
      GPHASE(0, 0, true, true)
      GPHASE(0, 1, false, true)
      GPHASE(1, 1, true, false)
      GPHASE(1, 0, false, true)
    } else {
      GPHASE(0, 0, true, true)
      GPHASE(0, 1, false, true)
    }
  }
}

// ---------- QKV projection, 128x256 tiles (768 blocks = 3 exact waves),
// fused N=3072; V written directly transposed ----------
__global__ __launch_bounds__(512, 2) void k_gemm_qkv(
    const u16* __restrict__ A, const u16* __restrict__ W,
    const float* __restrict__ bq, const float* __restrict__ bk,
    const float* __restrict__ bv, u16* __restrict__ qkv,
    u16* __restrict__ vt) {
  const int bid = blockIdx.x;                  // 768 blocks
  const int xw = (bid & 7) * 96 + (bid >> 3);  // bijective XCD chunking
  const int mtile = xw / 12, ntile = xw % 12;  // same-mtile neighbors share A
  const int m0 = mtile * 128, n0 = ntile * 256;
  const int z = n0 >> 10;
  const float* bias = (z == 0) ? bq : (z == 1) ? bk : bv;
  u16* out = qkv + (size_t)z * 8388608;
  // q: fold 1/sqrt(64) AND log2(e) (attention softmax runs in exp2 domain)
  const float scl = (z == 0) ? 0.125f * 1.44269504088896340736f : 1.0f;
  f32x4 acc[4][4];
  gemm_core<4, 4>(A, W, m0, n0, acc);
  const int tid = threadIdx.x;
  const int wave = tid >> 6, lane = tid & 63;
  const int quad = lane >> 4, l16 = lane & 15;
  const int wr = wave >> 2, wn = wave & 3;
  if (z == 2) {
    // V -> vt [B,H,Dh,T] directly; r-loop spans 4 consecutive t -> uint2
    #pragma unroll
    for (int mt = 0; mt < 4; ++mt) {
      #pragma unroll
      for (int nt = 0; nt < 4; ++nt) {
        int nn = (n0 + wn * 64 + nt * 16 + l16) & 1023;
        float bn = bias[nn];
        int h = nn >> 6, d = nn & 63;
        int mbase = m0 + wr * 64 + mt * 16 + quad * 4;
        int b = mbase >> 11, tb = mbase & 2047;
        uint2 pk;
        pk.x = cvtpk(acc[mt][nt][0] + bn, acc[mt][nt][1] + bn);
        pk.y = cvtpk(acc[mt][nt][2] + bn, acc[mt][nt][3] + bn);
        *(uint2*)(vt + ((size_t)(b * NH + h) * 64 + d) * 2048 + tb) = pk;
      }
    }
  } else {
    #pragma unroll
    for (int mt = 0; mt < 4; ++mt) {
      #pragma unroll
      for (int nt = 0; nt < 4; ++nt) {
        int nn = (n0 + wn * 64 + nt * 16 + l16) & 1023;
        float bn = bias[nn];
        int h = nn >> 6, d = nn & 63;
        #pragma unroll
        for (int r = 0; r < 4; ++r) {
          int m = m0 + wr * 64 + mt * 16 + quad * 4 + r;
          int b = m >> 11, tt = m & 2047;
          float val = (acc[mt][nt][r] + bn) * scl;
          out[(((size_t)(b * NH + h) * 2048 + tt) << 6) + d] = (u16)f2bf(val);
        }
      }
    }
  }
}

// ---------- output projection: 128x256 tiles -> 256 blocks, 16-MFMA phases --
__global__ __launch_bounds__(512, 2) void k_gemm_out(
    const u16* __restrict__ A, const u16* __restrict__ Bw,
    const float* __restrict__ bias, float* __restrict__ out) {
  const int bid = blockIdx.x;                 // 256 blocks
  const int sw = (bid & 7) * 32 + (bid >> 3); // XCD chunking: same mtiles/XCD
  const int mtile = sw >> 2, ntile = sw & 3;
  const int m0 = mtile * 128, n0 = ntile * 256;
  f32x4 acc[4][4];
  gemm_core<4, 4>(A, Bw, m0, n0, acc);
  const int tid = threadIdx.x;
  const int wave = tid >> 6, lane = tid & 63;
  const int quad = lane >> 4, l16 = lane & 15;
  const int wr = wave >> 2, wn = wave & 3;
  #pragma unroll
  for (int mt = 0; mt < 4; ++mt) {
    #pragma unroll
    for (int nt = 0; nt < 4; ++nt) {
      int n = n0 + wn * 64 + nt * 16 + l16;
      float bn = bias[n];
      #pragma unroll
      for (int r = 0; r < 4; ++r) {
        int m = m0 + wr * 64 + mt * 16 + quad * 4 + r;
        out[(size_t)m * 1024 + n] = acc[mt][nt][r] + bn;
      }
    }
  }
}

// ---------- flash attention R10: dbuf LDS (gload_lds staging, XOR-granule)
// + fused A/B sub-steps sharing K/V fragments (16 ds_reads/step vs 32) +
// amdgpu_waves_per_eu(4,4) so the allocator uses up to 128 VGPR instead of
// squeezing to 64 + spilling (the R2/R9 failure). Single barrier per step.
#define QK_STEP(KF, QF0, QF1, ST, DIAG)                                        \
  {                                                                            \
    _Pragma("unroll")                                                          \
    for (int nt = 0; nt < 4; ++nt) {                                           \
      f32x4 z4 = {0.f, 0.f, 0.f, 0.f};                                         \
      z4 = __builtin_amdgcn_mfma_f32_16x16x32_bf16(KF[nt][0], QF0, z4, 0, 0, 0); \
      ST[nt] = __builtin_amdgcn_mfma_f32_16x16x32_bf16(KF[nt][1], QF1, z4, 0, 0, 0); \
    }                                                                          \
    if (DIAG) {                                                                \
      int q_loc = wave * 16 + l16;                                             \
      _Pragma("unroll")                                                        \
      for (int nt = 0; nt < 4; ++nt) {                                         \
        _Pragma("unroll")                                                      \
        for (int r = 0; r < 4; ++r) {                                          \
          int k_loc = nt * 16 + quad * 4 + r;                                  \
          if (k_loc > q_loc) ST[nt][r] = -1e30f;                               \
        }                                                                      \
      }                                                                        \
    }                                                                          \
  }

#define SM_STEP(ST, MI, LI, O, PF0, PF1)                                       \
  {                                                                            \
    float mq[4];                                                               \
    _Pragma("unroll")                                                          \
    for (int nt = 0; nt < 4; ++nt)                                             \
      mq[nt] = fmaxf(fmaxf(ST[nt][0], ST[nt][1]), fmaxf(ST[nt][2], ST[nt][3]));\
    float mx = fmaxf(fmaxf(mq[0], mq[1]), fmaxf(mq[2], mq[3]));                \
    mx = fmaxf(mx, __shfl_xor(mx, 16, 64));                                    \
    mx = fmaxf(mx, __shfl_xor(mx, 32, 64));                                    \
    float mnew = fmaxf(MI, mx);                                                \
    float alpha = EXP2(MI - mnew);                                             \
    MI = mnew;                                                                 \
    LI *= alpha;                                                               \
    _Pragma("unroll")                                                          \
    for (int r = 0; r < 4; ++r) {                                              \
      float av = __shfl(alpha, quad * 4 + r, 16);                              \
      _Pragma("unroll")                                                        \
      for (int dt = 0; dt < 4; ++dt) O[dt][r] *= av;                           \
    }                                                                          \
    u32 Wx[4], Wy[4];                                                          \
    float sq[4];                                                               \
    _Pragma("unroll")                                                          \
    for (int nt = 0; nt < 4; ++nt) {                                           \
      float p0 = EXP2(ST[nt][0] - mnew);                                       \
      float p1 = EXP2(ST[nt][1] - mnew);                                       \
      float p2 = EXP2(ST[nt][2] - mnew);                                       \
      float p3 = EXP2(ST[nt][3] - mnew);                                       \
      sq[nt] = (p0 + p1) + (p2 + p3);                                          \
      Wx[nt] = cvtpk(p0, p1);                                                  \
      Wy[nt] = cvtpk(p2, p3);                                                  \
    }                                                                          \
    float sum = (sq[0] + sq[1]) + (sq[2] + sq[3]);                             \
    sum += __shfl_xor(sum, 16, 64);                                            \
    sum += __shfl_xor(sum, 32, 64);                                            \
    LI += sum;                                                                 \
    uint4 t0, t1;                                                              \
    {                                                                          \
      u32 e, f;                                                                \
      e = __shfl(Wx[0], s0, 64); f = __shfl(Wx[1], s0, 64); t0.x = hi ? f : e; \
      e = __shfl(Wy[0], s0, 64); f = __shfl(Wy[1], s0, 64); t0.y = hi ? f : e; \
      e = __shfl(Wx[0], s1, 64); f = __shfl(Wx[1], s1, 64); t0.z = hi ? f : e; \
      e = __shfl(Wy[0], s1, 64); f = __shfl(Wy[1], s1, 64); t0.w = hi ? f : e; \
      e = __shfl(Wx[2], s0, 64); f = __shfl(Wx[3], s0, 64); t1.x = hi ? f : e; \
      e = __shfl(Wy[2], s0, 64); f = __shfl(Wy[3], s0, 64); t1.y = hi ? f : e; \
      e = __shfl(Wx[2], s1, 64); f = __shfl(Wx[3], s1, 64); t1.z = hi ? f : e; \
      e = __shfl(Wy[2], s1, 64); f = __shfl(Wy[3], s1, 64); t1.w = hi ? f : e; \
    }                                                                          \
    PF0 = __builtin_bit_cast(short8, t0);                                      \
    PF1 = __builtin_bit_cast(short8, t1);                                      \
  }

#define PV_STEP(VF, PF0, PF1, O)                                               \
  {                                                                            \
    _Pragma("unroll")                                                          \
    for (int dt = 0; dt < 4; ++dt) {                                           \
      O[dt] = __builtin_amdgcn_mfma_f32_16x16x32_bf16(PF0, VF[dt][0], O[dt], 0, 0, 0); \
      O[dt] = __builtin_amdgcn_mfma_f32_16x16x32_bf16(PF1, VF[dt][1], O[dt], 0, 0, 0); \
    }                                                                          \
  }

#define ATTN_EPI(O, LI, QT)                                                    \
  _Pragma("unroll")                                                            \
  for (int r = 0; r < 4; ++r) {                                                \
    float lv = __shfl(LI, quad * 4 + r, 16);                                   \
    float inv = 1.0f / lv;                                                     \
    int t = (QT) * 64 + wave * 16 + quad * 4 + r;                              \
    _Pragma("unroll")                                                          \
    for (int dt = 0; dt < 4; ++dt) {                                           \
      int d = dt * 16 + l16;                                                   \
      y[(((size_t)b * 2048 + t) * NH + h) * 64 + d] = (u16)f2bf(O[dt][r] * inv); \
    }                                                                          \
  }

// stage tile KT into buffer PB: 4 gload_lds16/thread, wave-split, XOR-granule
#define ATTN_STAGE(PB, KT)                                                     \
  {                                                                            \
    const u16* kk = kbase + (size_t)(KT) * 4096;                               \
    const u16* vv = vbase + (size_t)(KT) * 64;                                 \
    gload_lds16(kk + koff0, &Ks[PB][wave * 512]);                              \
    gload_lds16(kk + koff1, &Ks[PB][2048 + wave * 512]);                       \
    gload_lds16(vv + voff0, &Vs[PB][wave * 512]);                              \
    gload_lds16(vv + voff1, &Vs[PB][2048 + wave * 512]);                       \
  }

__global__ __attribute__((amdgpu_flat_work_group_size(256, 256),
                          amdgpu_waves_per_eu(4, 4))) void k_attn(
    const u16* __restrict__ q, const u16* __restrict__ k,
    const u16* __restrict__ vt, u16* __restrict__ y) {
  const int tid = threadIdx.x;
  const int wave = tid >> 6, lane = tid & 63;
  const int quad = lane >> 4, l16 = lane & 15;
  const int bh = blockIdx.x, bx = blockIdx.y;  // grid (64,16): id%8 = bh%8
  const int qtB = bx, qtA = 31 - bx;           // qtB in 0..15, qtA in 16..31
  const int b = bh >> 4, h = bh & 15;

  __shared__ u16 Ks[2][4096];                  // [k-row 0..63][64] XOR-granule
  __shared__ u16 Vs[2][4096];                  // [d 0..63][64]

  const u16* qbA = q + ((size_t)bh * 2048 + qtA * 64 + wave * 16 + l16) * 64;
  short8 qA0 = *(const short8*)(qbA + quad * 8);
  short8 qA1 = *(const short8*)(qbA + 32 + quad * 8);
  const u16* qbB = q + ((size_t)bh * 2048 + qtB * 64 + wave * 16 + l16) * 64;
  short8 qB0 = *(const short8*)(qbB + quad * 8);
  short8 qB1 = *(const short8*)(qbB + 32 + quad * 8);

  f32x4 oA[4], oB[4];
  {
    f32x4 z = {0.f, 0.f, 0.f, 0.f};
    #pragma unroll
    for (int dt = 0; dt < 4; ++dt) { oA[dt] = z; oB[dt] = z; }
  }
  float mA = -1e30f, lA = 0.f, mB = -1e30f, lB = 0.f;

  const u16* kbase = k + (size_t)bh * 131072;
  const u16* vbase = vt + (size_t)bh * 131072;

  // staging source offsets: lane L covers local row L>>3, granule (L&7)^(L>>3)
  const int srow8 = lane >> 3;
  const int sg = (lane & 7) ^ srow8;
  const int r0a = wave * 8 + srow8, r0b = r0a + 32;
  const int koff0 = r0a * 64 + sg * 8, koff1 = r0b * 64 + sg * 8;
  const int voff0 = r0a * 2048 + sg * 8, voff1 = r0b * 2048 + sg * 8;

  // fragment-read swizzle: logical granule g at row r stored at g^(r&7)
  const int fsw = l16 & 7;

  // P-exchange source lanes [verified R3]
  const int s0 = ((quad & 1) << 5) + l16, s1 = s0 + 16;
  const int hi = quad >> 1;

  ATTN_STAGE(0, 0)
  __syncthreads();

  for (int kt = 0; kt <= qtA; ++kt) {
    const int p = kt & 1;
    if (kt < qtA) ATTN_STAGE(p ^ 1, kt + 1)

    // K fragments (shared by A and B): logical granules quad and quad^4
    short8 kf[4][2];
    #pragma unroll
    for (int nt = 0; nt < 4; ++nt) {
      int base = (nt * 16 + l16) * 64 + ((quad ^ fsw) * 8);
      kf[nt][0] = *(const short8*)(&Ks[p][base]);
      kf[nt][1] = *(const short8*)(&Ks[p][base ^ 32]);
    }
    const bool doB = (kt <= qtB);
    f32x4 stA[4], stB[4];
    QK_STEP(kf, qA0, qA1, stA, (kt == qtA))
    if (doB) { QK_STEP(kf, qB0, qB1, stB, (kt == qtB)) }

    short8 pfA0, pfA1, pfB0, pfB1;
    SM_STEP(stA, mA, lA, oA, pfA0, pfA1)

    // V fragments (shared by A and B), loaded after stA dies
    short8 vf[4][2];
    #pragma unroll
    for (int dt = 0; dt < 4; ++dt) {
      int base = (dt * 16 + l16) * 64 + ((quad ^ fsw) * 8);
      vf[dt][0] = *(const short8*)(&Vs[p][base]);
      vf[dt][1] = *(const short8*)(&Vs[p][base ^ 32]);
    }
    if (doB) { SM_STEP(stB, mB, lB, oB, pfB0, pfB1) }

    PV_STEP(vf, pfA0, pfA1, oA)
    if (doB) { PV_STEP(vf, pfB0, pfB1, oB) }

    __syncthreads();  // drains this step's gloads (issued ~600cy ago) + swaps
  }

  ATTN_EPI(oA, lA, qtA)
  ATTN_EPI(oB, lB, qtB)
}

extern "C" void kernel_launch(void* const* d_in, const int* in_sizes, int n_in,
                              void* d_out, int out_size, void* d_ws, size_t ws_size,
                              hipStream_t stream) {
  const float* x  = (const float*)d_in[0];
  const float* Wq = (const float*)d_in[1];
  const float* bq = (const float*)d_in[2];
  const float* Wk = (const float*)d_in[3];
  const float* bk = (const float*)d_in[4];
  const float* Wv = (const float*)d_in[5];
  const float* bv = (const float*)d_in[6];
  const float* Wo = (const float*)d_in[7];
  const float* bo = (const float*)d_in[8];
  float* out = (float*)d_out;

  u16* ws  = (u16*)d_ws;
  u16* xb  = ws;                   // 8388608   x bf16 [8192][1024]
  u16* Wb  = ws + 8388608;         // 4x1048576 Wq|Wk|Wv|Wo bf16
  u16* qkv = ws + 12582912;        // 3x8388608 q|k (v region unused now)
  u16* vt  = ws + 37748736;        // 8388608   v^T [B,H,Dh,T] bf16
  u16* y   = ws + 46137344;        // 8388608   attn out [B,T,H,Dh] bf16

  k_convert<<<dim3(12288), dim3(256), 0, stream>>>(x, Wq, Wk, Wv, Wo, ws);
  k_gemm_qkv<<<dim3(768), dim3(512), 0, stream>>>(xb, Wb, bq, bk, bv, qkv, vt);
  k_attn<<<dim3(64, 16), dim3(256), 0, stream>>>(qkv, qkv + 8388608, vt, y);
  k_gemm_out<<<dim3(256), dim3(512), 0, stream>>>(y, Wb + 3 * 1048576, bo, out);
}

// Round 12
// 313.002 us; speedup vs baseline: 1.7792x; 1.7792x over previous
//
#include <hip/hip_runtime.h>

typedef __attribute__((ext_vector_type(8))) short short8;
typedef __attribute__((ext_vector_type(4))) float f32x4;
typedef unsigned short u16;
typedef unsigned int u32;

#define NH 16

#if __has_builtin(__builtin_amdgcn_exp2f)
#define EXP2(x) __builtin_amdgcn_exp2f(x)
#else
#define EXP2(x) exp2f(x)
#endif

__device__ __forceinline__ u32 f2bf(float f) {
  u32 u = __builtin_bit_cast(u32, f);
  return (u + 0x7fffu + ((u >> 16) & 1u)) >> 16;  // round-nearest-even bf16 bits
}

// v_cvt_pk_bf16_f32: two f32 -> packed bf16x2 (RNE), one instruction.
__device__ __forceinline__ u32 cvtpk(float lo, float hi) {
  u32 r;
  asm("v_cvt_pk_bf16_f32 %0, %1, %2" : "=v"(r) : "v"(lo), "v"(hi));
  return r;
}

// async global->LDS, 16B per lane. LDS dest is wave-uniform base + lane*16.
__device__ __forceinline__ void gload_lds16(const u16* g, u16* l) {
  __builtin_amdgcn_global_load_lds(
      (const __attribute__((address_space(1))) void*)g,
      (__attribute__((address_space(3))) void*)l, 16, 0, 0);
}

// ---------- convert x + Wq,Wk,Wv,Wo (fp32) -> bf16 into ws ----------
__global__ __launch_bounds__(256) void k_convert(
    const float* __restrict__ x, const float* __restrict__ wq,
    const float* __restrict__ wk, const float* __restrict__ wv,
    const float* __restrict__ wo, u16* __restrict__ dst) {
  int i = blockIdx.x * 256 + threadIdx.x;
  size_t e = (size_t)i * 4;
  const float* s; size_t off;
  if (e < 8388608ull)       { s = x;  off = e; }
  else if (e < 9437184ull)  { s = wq; off = e - 8388608ull; }
  else if (e < 10485760ull) { s = wk; off = e - 9437184ull; }
  else if (e < 11534336ull) { s = wv; off = e - 10485760ull; }
  else                      { s = wo; off = e - 11534336ull; }
  float4 d = *(const float4*)(s + off);
  uint2 o;
  o.x = cvtpk(d.x, d.y);
  o.y = cvtpk(d.z, d.w);
  *(uint2*)(dst + e) = o;
}

// ---------- 8-wave 128x256 GEMM core (T3+T4), per-phase staggered staging --
// 512 threads = 8 waves (2M x 4N). BM=128, BN=256, BK=64, K=1024. True dbuf
// LDS; gload_lds16 with constant-per-lane granule XOR swizzle. R12: the 6
// staging loads split into two 3-load halves issued before phase 0 and
// BETWEEN phases (m196 fine interleave); vmcnt(3) at tile top waits exactly
// the previous tile's trailing half (ordered retirement, m135) while the
// next tile's first half stays in flight. Never drains to 0 in-loop.
#define GP44(NH_, LA)                                                          \
  if (LA) {                                                                    \
    _Pragma("unroll")                                                          \
    for (int mt = 0; mt < 4; ++mt)                                             \
      _Pragma("unroll")                                                        \
      for (int ks = 0; ks < 2; ++ks)                                           \
        af[mt][ks] = *(const short8*)(Ab + (wr * 64 + mt * 16 + l16) * 64 +    \
                                      ((ks * 4 + quad) ^ swz) * 8);            \
  }                                                                            \
  _Pragma("unroll")                                                            \
  for (int nt = 0; nt < 2; ++nt)                                               \
    _Pragma("unroll")                                                          \
    for (int ks = 0; ks < 2; ++ks)                                             \
      bfr[nt][ks] = *(const short8*)(                                          \
          Bb + (wn * 64 + ((NH_) * 2 + nt) * 16 + l16) * 64 +                  \
          ((ks * 4 + quad) ^ swz) * 8);                                        \
  __builtin_amdgcn_s_barrier();                                                \
  __builtin_amdgcn_s_setprio(1);                                               \
  _Pragma("unroll")                                                            \
  for (int mt = 0; mt < 4; ++mt)                                               \
    _Pragma("unroll")                                                          \
    for (int nt = 0; nt < 2; ++nt)                                             \
      _Pragma("unroll")                                                        \
      for (int ks = 0; ks < 2; ++ks)                                           \
        acc[mt][(NH_) * 2 + nt] = __builtin_amdgcn_mfma_f32_16x16x32_bf16(     \
            af[mt][ks], bfr[nt][ks], acc[mt][(NH_) * 2 + nt], 0, 0, 0);        \
  __builtin_amdgcn_s_setprio(0);                                               \
  __builtin_amdgcn_s_barrier();                                                \
  __builtin_amdgcn_sched_barrier(0);

// staging halves: H0 = {A rows 0-63, B rows 0-127}, H1 = {A 64-127, B 128-255}
#define SH0(T, PB)                                                             \
  {                                                                            \
    const u16* aT = aTh + (T) * 64;                                            \
    const u16* bT = bTh + (T) * 64;                                            \
    gload_lds16(aT, &As[PB][dbase]);                                           \
    gload_lds16(bT, &Bs[PB][dbase]);                                           \
    gload_lds16(bT + 65536, &Bs[PB][dbase + 4096]);                            \
  }
#define SH1(T, PB)                                                             \
  {                                                                            \
    const u16* aT = aTh + (T) * 64;                                            \
    const u16* bT = bTh + (T) * 64;                                            \
    gload_lds16(aT + 65536, &As[PB][dbase + 4096]);                            \
    gload_lds16(bT + 131072, &Bs[PB][dbase + 8192]);                           \
    gload_lds16(bT + 196608, &Bs[PB][dbase + 12288]);                          \
  }

__device__ __forceinline__ void gemm_core44(const u16* __restrict__ Aptr,
                                            const u16* __restrict__ Bptr,
                                            int m0, int n0,
                                            f32x4 (&acc)[4][4]) {
  __shared__ u16 As[2][8192];    // [128][64] granule-XOR
  __shared__ u16 Bs[2][16384];   // [256][64] granule-XOR
  const int tid = threadIdx.x;
  const int wave = tid >> 6, lane = tid & 63;
  const int quad = lane >> 4, l16 = lane & 15;
  const int wr = wave >> 2, wn = wave & 3;
  const int swz = l16 & 7;
  const int srow = tid >> 3;
  const int srcg = (tid & 7) ^ (srow & 7);
  const u16* aTh = Aptr + (size_t)(m0 + srow) * 1024 + srcg * 8;
  const u16* bTh = Bptr + (size_t)(n0 + srow) * 1024 + srcg * 8;
  const int dbase = wave * 512;

  {
    f32x4 z = {0.f, 0.f, 0.f, 0.f};
    #pragma unroll
    for (int a = 0; a < 4; ++a)
      #pragma unroll
      for (int b2 = 0; b2 < 4; ++b2) acc[a][b2] = z;
  }

  SH0(0, 0)
  SH1(0, 0)

  short8 af[4][2], bfr[2][2];
  for (int t = 0; t < 16; ++t) {
    const int p = t & 1;
    if (t < 15) {
      SH0(t + 1, p ^ 1)
      asm volatile("s_waitcnt vmcnt(3)" ::: "memory");
    } else {
      asm volatile("s_waitcnt vmcnt(0)" ::: "memory");
    }
    __builtin_amdgcn_s_barrier();
    __builtin_amdgcn_sched_barrier(0);
    const u16* Ab = &As[p][0];
    const u16* Bb = &Bs[p][0];
    GP44(0, true)
    if (t < 15) SH1(t + 1, p ^ 1)
    GP44(1, false)
  }
}

// ---------- QKV projection, 128x256 tiles (768 blocks = 3 exact waves),
// fused N=3072; V written directly transposed ----------
__global__ __launch_bounds__(512, 2) void k_gemm_qkv(
    const u16* __restrict__ A, const u16* __restrict__ W,
    const float* __restrict__ bq, const float* __restrict__ bk,
    const float* __restrict__ bv, u16* __restrict__ qkv,
    u16* __restrict__ vt) {
  const int bid = blockIdx.x;                  // 768 blocks
  const int xw = (bid & 7) * 96 + (bid >> 3);  // bijective XCD chunking
  const int mtile = xw / 12, ntile = xw % 12;  // same-mtile neighbors share A
  const int m0 = mtile * 128, n0 = ntile * 256;
  const int z = n0 >> 10;
  const float* bias = (z == 0) ? bq : (z == 1) ? bk : bv;
  u16* out = qkv + (size_t)z * 8388608;
  // q: fold 1/sqrt(64) AND log2(e) (attention softmax runs in exp2 domain)
  const float scl = (z == 0) ? 0.125f * 1.44269504088896340736f : 1.0f;
  f32x4 acc[4][4];
  gemm_core44(A, W, m0, n0, acc);
  const int tid = threadIdx.x;
  const int wave = tid >> 6, lane = tid & 63;
  const int quad = lane >> 4, l16 = lane & 15;
  const int wr = wave >> 2, wn = wave & 3;
  if (z == 2) {
    // V -> vt [B,H,Dh,T] directly; r-loop spans 4 consecutive t -> uint2
    #pragma unroll
    for (int mt = 0; mt < 4; ++mt) {
      #pragma unroll
      for (int nt = 0; nt < 4; ++nt) {
        int nn = (n0 + wn * 64 + nt * 16 + l16) & 1023;
        float bn = bias[nn];
        int h = nn >> 6, d = nn & 63;
        int mbase = m0 + wr * 64 + mt * 16 + quad * 4;
        int b = mbase >> 11, tb = mbase & 2047;
        uint2 pk;
        pk.x = cvtpk(acc[mt][nt][0] + bn, acc[mt][nt][1] + bn);
        pk.y = cvtpk(acc[mt][nt][2] + bn, acc[mt][nt][3] + bn);
        *(uint2*)(vt + ((size_t)(b * NH + h) * 64 + d) * 2048 + tb) = pk;
      }
    }
  } else {
    #pragma unroll
    for (int mt = 0; mt < 4; ++mt) {
      #pragma unroll
      for (int nt = 0; nt < 4; ++nt) {
        int nn = (n0 + wn * 64 + nt * 16 + l16) & 1023;
        float bn = bias[nn];
        int h = nn >> 6, d = nn & 63;
        #pragma unroll
        for (int r = 0; r < 4; ++r) {
          int m = m0 + wr * 64 + mt * 16 + quad * 4 + r;
          int b = m >> 11, tt = m & 2047;
          float val = (acc[mt][nt][r] + bn) * scl;
          out[(((size_t)(b * NH + h) * 2048 + tt) << 6) + d] = (u16)f2bf(val);
        }
      }
    }
  }
}

// ---------- output projection: 128x256 tiles -> 256 blocks ----------
__global__ __launch_bounds__(512, 2) void k_gemm_out(
    const u16* __restrict__ A, const u16* __restrict__ Bw,
    const float* __restrict__ bias, float* __restrict__ out) {
  const int bid = blockIdx.x;                 // 256 blocks
  const int sw = (bid & 7) * 32 + (bid >> 3); // XCD chunking: same mtiles/XCD
  const int mtile = sw >> 2, ntile = sw & 3;
  const int m0 = mtile * 128, n0 = ntile * 256;
  f32x4 acc[4][4];
  gemm_core44(A, Bw, m0, n0, acc);
  const int tid = threadIdx.x;
  const int wave = tid >> 6, lane = tid & 63;
  const int quad = lane >> 4, l16 = lane & 15;
  const int wr = wave >> 2, wn = wave & 3;
  #pragma unroll
  for (int mt = 0; mt < 4; ++mt) {
    #pragma unroll
    for (int nt = 0; nt < 4; ++nt) {
      int n = n0 + wn * 64 + nt * 16 + l16;
      float bn = bias[n];
      #pragma unroll
      for (int r = 0; r < 4; ++r) {
        int m = m0 + wr * 64 + mt * 16 + quad * 4 + r;
        out[(size_t)m * 1024 + n] = acc[mt][nt][r] + bn;
      }
    }
  }
}

// ---------- flash attention (R8-verified, 101.4us / VGPR 64 / no spill):
// S^T orientation, paired q-tiles, SEQUENTIAL A/B sub-steps (fused variants
// spill — R2/R9/R11), in-register P exchange, dbuf K/V LDS (1 barrier/step),
// same-bh-per-XCD grid for L2 K/V residency, cvt_pk bf16 pack. ----------
#define ATTN_SUB(P, QF0, QF1, O, MI, LI, DIAG)                                 \
  {                                                                            \
    f32x4 st[4];                                                               \
    _Pragma("unroll")                                                          \
    for (int nt = 0; nt < 4; ++nt) {                                           \
      short8 kf0 = *(const short8*)(&Ks[P][(nt * 16 + l16) * 72 + quad * 8]);  \
      short8 kf1 = *(const short8*)(&Ks[P][(nt * 16 + l16) * 72 + 32 + quad * 8]); \
      f32x4 z4 = {0.f, 0.f, 0.f, 0.f};                                         \
      z4 = __builtin_amdgcn_mfma_f32_16x16x32_bf16(kf0, QF0, z4, 0, 0, 0);     \
      st[nt] = __builtin_amdgcn_mfma_f32_16x16x32_bf16(kf1, QF1, z4, 0, 0, 0); \
    }                                                                          \
    if (DIAG) {                                                                \
      int q_loc = wave * 16 + l16;                                             \
      _Pragma("unroll")                                                        \
      for (int nt = 0; nt < 4; ++nt) {                                         \
        _Pragma("unroll")                                                      \
        for (int r = 0; r < 4; ++r) {                                          \
          int k_loc = nt * 16 + quad * 4 + r;                                  \
          if (k_loc > q_loc) st[nt][r] = -1e30f;                               \
        }                                                                      \
      }                                                                        \
    }                                                                          \
    float mq[4];                                                               \
    _Pragma("unroll")                                                          \
    for (int nt = 0; nt < 4; ++nt)                                             \
      mq[nt] = fmaxf(fmaxf(st[nt][0], st[nt][1]), fmaxf(st[nt][2], st[nt][3]));\
    float mx = fmaxf(fmaxf(mq[0], mq[1]), fmaxf(mq[2], mq[3]));                \
    mx = fmaxf(mx, __shfl_xor(mx, 16, 64));                                    \
    mx = fmaxf(mx, __shfl_xor(mx, 32, 64));                                    \
    float mnew = fmaxf(MI, mx);                                                \
    float alpha = EXP2(MI - mnew);                                             \
    MI = mnew;                                                                 \
    LI *= alpha;                                                               \
    _Pragma("unroll")                                                          \
    for (int r = 0; r < 4; ++r) {                                              \
      float av = __shfl(alpha, quad * 4 + r, 16);                              \
      _Pragma("unroll")                                                        \
      for (int dt = 0; dt < 4; ++dt) O[dt][r] *= av;                           \
    }                                                                          \
    u32 Wx[4], Wy[4];                                                          \
    float sq[4];                                                               \
    _Pragma("unroll")                                                          \
    for (int nt = 0; nt < 4; ++nt) {                                           \
      float p0 = EXP2(st[nt][0] - mnew);                                       \
      float p1 = EXP2(st[nt][1] - mnew);                                       \
      float p2 = EXP2(st[nt][2] - mnew);                                       \
      float p3 = EXP2(st[nt][3] - mnew);                                       \
      sq[nt] = (p0 + p1) + (p2 + p3);                                          \
      Wx[nt] = cvtpk(p0, p1);                                                  \
      Wy[nt] = cvtpk(p2, p3);                                                  \
    }                                                                          \
    float sum = (sq[0] + sq[1]) + (sq[2] + sq[3]);                             \
    sum += __shfl_xor(sum, 16, 64);                                            \
    sum += __shfl_xor(sum, 32, 64);                                            \
    LI += sum;                                                                 \
    uint4 t0, t1;                                                              \
    {                                                                          \
      u32 e, f;                                                                \
      e = __shfl(Wx[0], s0, 64); f = __shfl(Wx[1], s0, 64); t0.x = hi ? f : e; \
      e = __shfl(Wy[0], s0, 64); f = __shfl(Wy[1], s0, 64); t0.y = hi ? f : e; \
      e = __shfl(Wx[0], s1, 64); f = __shfl(Wx[1], s1, 64); t0.z = hi ? f : e; \
      e = __shfl(Wy[0], s1, 64); f = __shfl(Wy[1], s1, 64); t0.w = hi ? f : e; \
      e = __shfl(Wx[2], s0, 64); f = __shfl(Wx[3], s0, 64); t1.x = hi ? f : e; \
      e = __shfl(Wy[2], s0, 64); f = __shfl(Wy[3], s0, 64); t1.y = hi ? f : e; \
      e = __shfl(Wx[2], s1, 64); f = __shfl(Wx[3], s1, 64); t1.z = hi ? f : e; \
      e = __shfl(Wy[2], s1, 64); f = __shfl(Wy[3], s1, 64); t1.w = hi ? f : e; \
    }                                                                          \
    short8 pf0 = __builtin_bit_cast(short8, t0);                               \
    short8 pf1 = __builtin_bit_cast(short8, t1);                               \
    _Pragma("unroll")                                                          \
    for (int dt = 0; dt < 4; ++dt) {                                           \
      short8 vf0 = *(const short8*)(&Vs[P][(dt * 16 + l16) * 72 + quad * 8]);  \
      short8 vf1 = *(const short8*)(&Vs[P][(dt * 16 + l16) * 72 + 32 + quad * 8]); \
      O[dt] = __builtin_amdgcn_mfma_f32_16x16x32_bf16(pf0, vf0, O[dt], 0, 0, 0); \
      O[dt] = __builtin_amdgcn_mfma_f32_16x16x32_bf16(pf1, vf1, O[dt], 0, 0, 0); \
    }                                                                          \
  }

#define ATTN_EPI(O, LI, QT)                                                    \
  _Pragma("unroll")                                                            \
  for (int r = 0; r < 4; ++r) {                                                \
    float lv = __shfl(LI, quad * 4 + r, 16);                                   \
    float inv = 1.0f / lv;                                                     \
    int t = (QT) * 64 + wave * 16 + quad * 4 + r;                              \
    _Pragma("unroll")                                                          \
    for (int dt = 0; dt < 4; ++dt) {                                           \
      int d = dt * 16 + l16;                                                   \
      y[(((size_t)b * 2048 + t) * NH + h) * 64 + d] = (u16)f2bf(O[dt][r] * inv); \
    }                                                                          \
  }

__global__ __launch_bounds__(256, 4) void k_attn(
    const u16* __restrict__ q, const u16* __restrict__ k,
    const u16* __restrict__ vt, u16* __restrict__ y) {
  const int tid = threadIdx.x;
  const int wave = tid >> 6, lane = tid & 63;
  const int quad = lane >> 4, l16 = lane & 15;
  const int bh = blockIdx.x, bx = blockIdx.y;  // grid (64,16): id%8 = bh%8
  const int qtB = bx, qtA = 31 - bx;           // qtB in 0..15, qtA in 16..31
  const int b = bh >> 4, h = bh & 15;

  __shared__ u16 Ks[2][64 * 72];
  __shared__ u16 Vs[2][64 * 72];               // [d][kidx]

  const u16* qbA = q + ((size_t)bh * 2048 + qtA * 64 + wave * 16 + l16) * 64;
  short8 qA0 = *(const short8*)(qbA + quad * 8);
  short8 qA1 = *(const short8*)(qbA + 32 + quad * 8);
  const u16* qbB = q + ((size_t)bh * 2048 + qtB * 64 + wave * 16 + l16) * 64;
  short8 qB0 = *(const short8*)(qbB + quad * 8);
  short8 qB1 = *(const short8*)(qbB + 32 + quad * 8);

  f32x4 oA[4], oB[4];
  {
    f32x4 z = {0.f, 0.f, 0.f, 0.f};
    #pragma unroll
    for (int dt = 0; dt < 4; ++dt) { oA[dt] = z; oB[dt] = z; }
  }
  float mA = -1e30f, lA = 0.f, mB = -1e30f, lB = 0.f;

  const u16* kbase = k + (size_t)bh * 131072;
  const u16* vbase = vt + (size_t)bh * 131072;
  const int r0 = tid >> 3, cc = tid & 7;
  // P-exchange source lanes: receiver (quad,ks) pulls W[2ks+hi] words from
  // lanes s0 (j=0..3) and s1 (j=4..7)  [verified R3]
  const int s0 = ((quad & 1) << 5) + l16, s1 = s0 + 16;
  const int hi = quad >> 1;

  // prologue: stage kt=0 into buffer 0
  {
    uint4 k0 = *(const uint4*)(kbase + (size_t)r0 * 64 + cc * 8);
    uint4 k1 = *(const uint4*)(kbase + (size_t)(r0 + 32) * 64 + cc * 8);
    uint4 v0 = *(const uint4*)(vbase + (size_t)r0 * 2048 + cc * 8);
    uint4 v1 = *(const uint4*)(vbase + (size_t)(r0 + 32) * 2048 + cc * 8);
    *(uint4*)(&Ks[0][r0 * 72 + cc * 8]) = k0;
    *(uint4*)(&Ks[0][(r0 + 32) * 72 + cc * 8]) = k1;
    *(uint4*)(&Vs[0][r0 * 72 + cc * 8]) = v0;
    *(uint4*)(&Vs[0][(r0 + 32) * 72 + cc * 8]) = v1;
  }
  __syncthreads();

  for (int kt = 0; kt <= qtA; ++kt) {
    const int p = kt & 1;
    const bool pre = (kt < qtA);
    uint4 kr0, kr1, vr0, vr1;
    if (pre) {  // issue next-tile loads early; consumed after compute
      const u16* kb = kbase + (size_t)(kt + 1) * 4096;
      const u16* vb = vbase + (kt + 1) * 64;
      kr0 = *(const uint4*)(kb + (size_t)r0 * 64 + cc * 8);
      kr1 = *(const uint4*)(kb + (size_t)(r0 + 32) * 64 + cc * 8);
      vr0 = *(const uint4*)(vb + (size_t)r0 * 2048 + cc * 8);
      vr1 = *(const uint4*)(vb + (size_t)(r0 + 32) * 2048 + cc * 8);
    }

    ATTN_SUB(p, qA0, qA1, oA, mA, lA, (kt == qtA))
    if (kt <= qtB) {
      ATTN_SUB(p, qB0, qB1, oB, mB, lB, (kt == qtB))
    }

    if (pre) {  // write next tile into the other buffer
      *(uint4*)(&Ks[p ^ 1][r0 * 72 + cc * 8]) = kr0;
      *(uint4*)(&Ks[p ^ 1][(r0 + 32) * 72 + cc * 8]) = kr1;
      *(uint4*)(&Vs[p ^ 1][r0 * 72 + cc * 8]) = vr0;
      *(uint4*)(&Vs[p ^ 1][(r0 + 32) * 72 + cc * 8]) = vr1;
    }
    __syncthreads();  // single barrier: orders buf[p^1] writes + buf[p] reads
  }

  ATTN_EPI(oA, lA, qtA)
  ATTN_EPI(oB, lB, qtB)
}

extern "C" void kernel_launch(void* const* d_in, const int* in_sizes, int n_in,
                              void* d_out, int out_size, void* d_ws, size_t ws_size,
                              hipStream_t stream) {
  const float* x  = (const float*)d_in[0];
  const float* Wq = (const float*)d_in[1];
  const float* bq = (const float*)d_in[2];
  const float* Wk = (const float*)d_in[3];
  const float* bk = (const float*)d_in[4];
  const float* Wv = (const float*)d_in[5];
  const float* bv = (const float*)d_in[6];
  const float* Wo = (const float*)d_in[7];
  const float* bo = (const float*)d_in[8];
  float* out = (float*)d_out;

  u16* ws  = (u16*)d_ws;
  u16* xb  = ws;                   // 8388608   x bf16 [8192][1024]
  u16* Wb  = ws + 8388608;         // 4x1048576 Wq|Wk|Wv|Wo bf16
  u16* qkv = ws + 12582912;        // 3x8388608 q|k (v region unused now)
  u16* vt  = ws + 37748736;        // 8388608   v^T [B,H,Dh,T] bf16
  u16* y   = ws + 46137344;        // 8388608   attn out [B,T,H,Dh] bf16

  k_convert<<<dim3(12288), dim3(256), 0, stream>>>(x, Wq, Wk, Wv, Wo, ws);
  k_gemm_qkv<<<dim3(768), dim3(512), 0, stream>>>(xb, Wb, bq, bk, bv, qkv, vt);
  k_attn<<<dim3(64, 16), dim3(256), 0, stream>>>(qkv, qkv + 8388608, vt, y);
  k_gemm_out<<<dim3(256), dim3(512), 0, stream>>>(y, Wb + 3 * 1048576, bo, out);
}

// Round 13
// 264.084 us; speedup vs baseline: 2.1088x; 1.1852x over previous
//
#include <hip/hip_runtime.h>

typedef __attribute__((ext_vector_type(8))) short short8;
typedef __attribute__((ext_vector_type(4))) float f32x4;
typedef unsigned short u16;
typedef unsigned int u32;

#define NH 16

#if __has_builtin(__builtin_amdgcn_exp2f)
#define EXP2(x) __builtin_amdgcn_exp2f(x)
#else
#define EXP2(x) exp2f(x)
#endif

__device__ __forceinline__ u32 f2bf(float f) {
  u32 u = __builtin_bit_cast(u32, f);
  return (u + 0x7fffu + ((u >> 16) & 1u)) >> 16;  // round-nearest-even bf16 bits
}

// v_cvt_pk_bf16_f32: two f32 -> packed bf16x2 (RNE), one instruction.
__device__ __forceinline__ u32 cvtpk(float lo, float hi) {
  u32 r;
  asm("v_cvt_pk_bf16_f32 %0, %1, %2" : "=v"(r) : "v"(lo), "v"(hi));
  return r;
}

// async global->LDS, 16B per lane. LDS dest is wave-uniform base + lane*16.
__device__ __forceinline__ void gload_lds16(const u16* g, u16* l) {
  __builtin_amdgcn_global_load_lds(
      (const __attribute__((address_space(1))) void*)g,
      (__attribute__((address_space(3))) void*)l, 16, 0, 0);
}

// ---------- convert x + Wq,Wk,Wv,Wo (fp32) -> bf16 into ws ----------
__global__ __launch_bounds__(256) void k_convert(
    const float* __restrict__ x, const float* __restrict__ wq,
    const float* __restrict__ wk, const float* __restrict__ wv,
    const float* __restrict__ wo, u16* __restrict__ dst) {
  int i = blockIdx.x * 256 + threadIdx.x;
  size_t e = (size_t)i * 4;
  const float* s; size_t off;
  if (e < 8388608ull)       { s = x;  off = e; }
  else if (e < 9437184ull)  { s = wq; off = e - 8388608ull; }
  else if (e < 10485760ull) { s = wk; off = e - 9437184ull; }
  else if (e < 11534336ull) { s = wv; off = e - 10485760ull; }
  else                      { s = wo; off = e - 11534336ull; }
  float4 d = *(const float4*)(s + off);
  uint2 o;
  o.x = cvtpk(d.x, d.y);
  o.y = cvtpk(d.z, d.w);
  *(uint2*)(dst + e) = o;
}

// ---------- parameterized 8-wave GEMM core (T3+T4): C = A * B^T ----------
// (R8-verified template.) 512 threads = 8 waves. BM = MT*32, BN = NT*64,
// BK = 64, K = 1024. True dbuf LDS; gload_lds16 staging with constant-per-
// lane granule XOR swizzle; T4 counted vmcnt (never drains to 0 in-loop);
// raw s_barrier only. R13: instantiated at <4,2> = 128x128 so LDS = 64 KB
// -> 2 blocks/CU (16 waves/CU) — R12 counters showed the 96 KB tile capped
// occupancy at 1 block/CU (20%) and that, not the schedule, was the wall.
#define GPHASE(MH, NH_, LA, LB)                                                \
  if (LA) {                                                                    \
    _Pragma("unroll")                                                          \
    for (int mt = 0; mt < 4; ++mt)                                             \
      _Pragma("unroll")                                                        \
      for (int ks = 0; ks < 2; ++ks)                                           \
        af[mt][ks] = *(const short8*)(Ab +                                     \
            (wr * MT * 16 + ((MH) * 4 + mt) * 16 + l16) * 64 +                 \
            ((ks * 4 + quad) ^ swz) * 8);                                      \
  }                                                                            \
  if (LB) {                                                                    \
    _Pragma("unroll")                                                          \
    for (int nt = 0; nt < NH2; ++nt)                                           \
      _Pragma("unroll")                                                        \
      for (int ks = 0; ks < 2; ++ks)                                           \
        bfr[nt][ks] = *(const short8*)(Bb +                                    \
            (wn * NT * 16 + ((NH_) * NH2 + nt) * 16 + l16) * 64 +              \
            ((ks * 4 + quad) ^ swz) * 8);                                      \
  }                                                                            \
  __builtin_amdgcn_s_barrier();                                                \
  __builtin_amdgcn_s_setprio(1);                                               \
  _Pragma("unroll")                                                            \
  for (int mt = 0; mt < 4; ++mt)                                               \
    _Pragma("unroll")                                                          \
    for (int nt = 0; nt < NH2; ++nt)                                           \
      _Pragma("unroll")                                                        \
      for (int ks = 0; ks < 2; ++ks)                                           \
        acc[(MH) * 4 + mt][(NH_) * NH2 + nt] =                                 \
            __builtin_amdgcn_mfma_f32_16x16x32_bf16(                           \
                af[mt][ks], bfr[nt][ks], acc[(MH) * 4 + mt][(NH_) * NH2 + nt], \
                0, 0, 0);                                                      \
  __builtin_amdgcn_s_setprio(0);                                               \
  __builtin_amdgcn_s_barrier();                                                \
  __builtin_amdgcn_sched_barrier(0);

#define STAGE_T(T, PB)                                                         \
  {                                                                            \
    const u16* aT = aTh + (T) * 64;                                            \
    const u16* bT = bTh + (T) * 64;                                            \
    u16* aD = &As[PB][0] + dbase;                                              \
    u16* bD = &Bs[PB][0] + dbase;                                              \
    _Pragma("unroll")                                                          \
    for (int j = 0; j < NLA; ++j) gload_lds16(aT + j * 65536, aD + j * 4096);  \
    _Pragma("unroll")                                                          \
    for (int j = 0; j < NLB; ++j) gload_lds16(bT + j * 65536, bD + j * 4096);  \
  }

template <int MT, int NT>
__device__ __forceinline__ void gemm_core(const u16* __restrict__ Aptr,
                                          const u16* __restrict__ Bptr,
                                          int m0, int n0,
                                          f32x4 (&acc)[MT][NT]) {
  constexpr int NLA = MT / 2;   // A gload_lds per thread per K-tile
  constexpr int NLB = NT;       // B gload_lds per thread per K-tile
  constexpr int NLD = NLA + NLB;
  constexpr int NH2 = NT / 2;
  __shared__ u16 As[2][MT * 32 * 64];
  __shared__ u16 Bs[2][NT * 64 * 64];
  const int tid = threadIdx.x;
  const int wave = tid >> 6, lane = tid & 63;
  const int quad = lane >> 4, l16 = lane & 15;
  const int wr = wave >> 2, wn = wave & 3;
  const int swz = l16 & 7;
  const int srow = tid >> 3;
  const int srcg = (tid & 7) ^ (srow & 7);
  const u16* aTh = Aptr + (size_t)(m0 + srow) * 1024 + srcg * 8;
  const u16* bTh = Bptr + (size_t)(n0 + srow) * 1024 + srcg * 8;
  const int dbase = wave * 512;

  {
    f32x4 z = {0.f, 0.f, 0.f, 0.f};
    #pragma unroll
    for (int a = 0; a < MT; ++a)
      #pragma unroll
      for (int b2 = 0; b2 < NT; ++b2) acc[a][b2] = z;
  }

  STAGE_T(0, 0)

  short8 af[4][2], bfr[NH2][2];
  for (int t = 0; t < 16; ++t) {
    const int p = t & 1;
    if (t < 15) {
      STAGE_T(t + 1, p ^ 1)
      if constexpr (NLD == 8)
        asm volatile("s_waitcnt vmcnt(8)" ::: "memory");
      else if constexpr (NLD == 6)
        asm volatile("s_waitcnt vmcnt(6)" ::: "memory");
      else if constexpr (NLD == 4)
        asm volatile("s_waitcnt vmcnt(4)" ::: "memory");
      else
        asm volatile("s_waitcnt vmcnt(0)" ::: "memory");
    } else {
      asm volatile("s_waitcnt vmcnt(0)" ::: "memory");
    }
    __builtin_amdgcn_s_barrier();
    __builtin_amdgcn_sched_barrier(0);
    const u16* Ab = &As[p][0];
    const u16* Bb = &Bs[p][0];
    if constexpr (MT == 8) {
      GPHASE(0, 0, true, true)
      GPHASE(0, 1, false, true)
      GPHASE(1, 1, true, false)
      GPHASE(1, 0, false, true)
    } else {
      GPHASE(0, 0, true, true)
      GPHASE(0, 1, false, true)
    }
  }
}

// ---------- QKV projection, 128x128 tiles (1536 blocks = 3 exact rounds at
// 2 blocks/CU), fused N=3072; V written directly transposed ----------
__global__ __launch_bounds__(512, 4) void k_gemm_qkv(
    const u16* __restrict__ A, const u16* __restrict__ W,
    const float* __restrict__ bq, const float* __restrict__ bk,
    const float* __restrict__ bv, u16* __restrict__ qkv,
    u16* __restrict__ vt) {
  const int bid = blockIdx.x;                   // 1536 blocks
  const int xw = (bid & 7) * 192 + (bid >> 3);  // bijective XCD chunking
  const int mtile = xw / 24, ntile = xw % 24;   // same-mtile neighbors share A
  const int m0 = mtile * 128, n0 = ntile * 128;
  const int z = n0 >> 10;
  const float* bias = (z == 0) ? bq : (z == 1) ? bk : bv;
  u16* out = qkv + (size_t)z * 8388608;
  // q: fold 1/sqrt(64) AND log2(e) (attention softmax runs in exp2 domain)
  const float scl = (z == 0) ? 0.125f * 1.44269504088896340736f : 1.0f;
  f32x4 acc[4][2];
  gemm_core<4, 2>(A, W, m0, n0, acc);
  const int tid = threadIdx.x;
  const int wave = tid >> 6, lane = tid & 63;
  const int quad = lane >> 4, l16 = lane & 15;
  const int wr = wave >> 2, wn = wave & 3;
  if (z == 2) {
    // V -> vt [B,H,Dh,T] directly; r-loop spans 4 consecutive t -> uint2
    #pragma unroll
    for (int mt = 0; mt < 4; ++mt) {
      #pragma unroll
      for (int nt = 0; nt < 2; ++nt) {
        int nn = (n0 + wn * 32 + nt * 16 + l16) & 1023;
        float bn = bias[nn];
        int h = nn >> 6, d = nn & 63;
        int mbase = m0 + wr * 64 + mt * 16 + quad * 4;
        int b = mbase >> 11, tb = mbase & 2047;
        uint2 pk;
        pk.x = cvtpk(acc[mt][nt][0] + bn, acc[mt][nt][1] + bn);
        pk.y = cvtpk(acc[mt][nt][2] + bn, acc[mt][nt][3] + bn);
        *(uint2*)(vt + ((size_t)(b * NH + h) * 64 + d) * 2048 + tb) = pk;
      }
    }
  } else {
    #pragma unroll
    for (int mt = 0; mt < 4; ++mt) {
      #pragma unroll
      for (int nt = 0; nt < 2; ++nt) {
        int nn = (n0 + wn * 32 + nt * 16 + l16) & 1023;
        float bn = bias[nn];
        int h = nn >> 6, d = nn & 63;
        #pragma unroll
        for (int r = 0; r < 4; ++r) {
          int m = m0 + wr * 64 + mt * 16 + quad * 4 + r;
          int b = m >> 11, tt = m & 2047;
          float val = (acc[mt][nt][r] + bn) * scl;
          out[(((size_t)(b * NH + h) * 2048 + tt) << 6) + d] = (u16)f2bf(val);
        }
      }
    }
  }
}

// ---------- output projection: 128x128 tiles -> 512 blocks = 1 exact round --
__global__ __launch_bounds__(512, 4) void k_gemm_out(
    const u16* __restrict__ A, const u16* __restrict__ Bw,
    const float* __restrict__ bias, float* __restrict__ out) {
  const int bid = blockIdx.x;                 // 512 blocks
  const int sw = (bid & 7) * 64 + (bid >> 3); // XCD chunking: same mtiles/XCD
  const int mtile = sw >> 3, ntile = sw & 7;
  const int m0 = mtile * 128, n0 = ntile * 128;
  f32x4 acc[4][2];
  gemm_core<4, 2>(A, Bw, m0, n0, acc);
  const int tid = threadIdx.x;
  const int wave = tid >> 6, lane = tid & 63;
  const int quad = lane >> 4, l16 = lane & 15;
  const int wr = wave >> 2, wn = wave & 3;
  #pragma unroll
  for (int mt = 0; mt < 4; ++mt) {
    #pragma unroll
    for (int nt = 0; nt < 2; ++nt) {
      int n = n0 + wn * 32 + nt * 16 + l16;
      float bn = bias[n];
      #pragma unroll
      for (int r = 0; r < 4; ++r) {
        int m = m0 + wr * 64 + mt * 16 + quad * 4 + r;
        out[(size_t)m * 1024 + n] = acc[mt][nt][r] + bn;
      }
    }
  }
}

// ---------- flash attention (R8-verified, 101.4us / VGPR 64 / no spill):
// S^T orientation, paired q-tiles, SEQUENTIAL A/B sub-steps (fused variants
// spill — R2/R9/R11), in-register P exchange, dbuf K/V LDS (1 barrier/step),
// same-bh-per-XCD grid for L2 K/V residency, cvt_pk bf16 pack. ----------
#define ATTN_SUB(P, QF0, QF1, O, MI, LI, DIAG)                                 \
  {                                                                            \
    f32x4 st[4];                                                               \
    _Pragma("unroll")                                                          \
    for (int nt = 0; nt < 4; ++nt) {                                           \
      short8 kf0 = *(const short8*)(&Ks[P][(nt * 16 + l16) * 72 + quad * 8]);  \
      short8 kf1 = *(const short8*)(&Ks[P][(nt * 16 + l16) * 72 + 32 + quad * 8]); \
      f32x4 z4 = {0.f, 0.f, 0.f, 0.f};                                         \
      z4 = __builtin_amdgcn_mfma_f32_16x16x32_bf16(kf0, QF0, z4, 0, 0, 0);     \
      st[nt] = __builtin_amdgcn_mfma_f32_16x16x32_bf16(kf1, QF1, z4, 0, 0, 0); \
    }                                                                          \
    if (DIAG) {                                                                \
      int q_loc = wave * 16 + l16;                                             \
      _Pragma("unroll")                                                        \
      for (int nt = 0; nt < 4; ++nt) {                                         \
        _Pragma("unroll")                                                      \
        for (int r = 0; r < 4; ++r) {                                          \
          int k_loc = nt * 16 + quad * 4 + r;                                  \
          if (k_loc > q_loc) st[nt][r] = -1e30f;                               \
        }                                                                      \
      }                                                                        \
    }                                                                          \
    float mq[4];                                                               \
    _Pragma("unroll")                                                          \
    for (int nt = 0; nt < 4; ++nt)                                             \
      mq[nt] = fmaxf(fmaxf(st[nt][0], st[nt][1]), fmaxf(st[nt][2], st[nt][3]));\
    float mx = fmaxf(fmaxf(mq[0], mq[1]), fmaxf(mq[2], mq[3]));                \
    mx = fmaxf(mx, __shfl_xor(mx, 16, 64));                                    \
    mx = fmaxf(mx, __shfl_xor(mx, 32, 64));                                    \
    float mnew = fmaxf(MI, mx);                                                \
    float alpha = EXP2(MI - mnew);                                             \
    MI = mnew;                                                                 \
    LI *= alpha;                                                               \
    _Pragma("unroll")                                                          \
    for (int r = 0; r < 4; ++r) {                                              \
      float av = __shfl(alpha, quad * 4 + r, 16);                              \
      _Pragma("unroll")                                                        \
      for (int dt = 0; dt < 4; ++dt) O[dt][r] *= av;                           \
    }                                                                          \
    u32 Wx[4], Wy[4];                                                          \
    float sq[4];                                                               \
    _Pragma("unroll")                                                          \
    for (int nt = 0; nt < 4; ++nt) {                                           \
      float p0 = EXP2(st[nt][0] - mnew);                                       \
      float p1 = EXP2(st[nt][1] - mnew);                                       \
      float p2 = EXP2(st[nt][2] - mnew);                                       \
      float p3 = EXP2(st[nt][3] - mnew);                                       \
      sq[nt] = (p0 + p1) + (p2 + p3);                                          \
      Wx[nt] = cvtpk(p0, p1);                                                  \
      Wy[nt] = cvtpk(p2, p3);                                                  \
    }                                                                          \
    float sum = (sq[0] + sq[1]) + (sq[2] + sq[3]);                             \
    sum += __shfl_xor(sum, 16, 64);                                            \
    sum += __shfl_xor(sum, 32, 64);                                            \
    LI += sum;                                                                 \
    uint4 t0, t1;                                                              \
    {                                                                          \
      u32 e, f;                                                                \
      e = __shfl(Wx[0], s0, 64); f = __shfl(Wx[1], s0, 64); t0.x = hi ? f : e; \
      e = __shfl(Wy[0], s0, 64); f = __shfl(Wy[1], s0, 64); t0.y = hi ? f : e; \
      e = __shfl(Wx[0], s1, 64); f = __shfl(Wx[1], s1, 64); t0.z = hi ? f : e; \
      e = __shfl(Wy[0], s1, 64); f = __shfl(Wy[1], s1, 64); t0.w = hi ? f : e; \
      e = __shfl(Wx[2], s0, 64); f = __shfl(Wx[3], s0, 64); t1.x = hi ? f : e; \
      e = __shfl(Wy[2], s0, 64); f = __shfl(Wy[3], s0, 64); t1.y = hi ? f : e; \
      e = __shfl(Wx[2], s1, 64); f = __shfl(Wx[3], s1, 64); t1.z = hi ? f : e; \
      e = __shfl(Wy[2], s1, 64); f = __shfl(Wy[3], s1, 64); t1.w = hi ? f : e; \
    }                                                                          \
    short8 pf0 = __builtin_bit_cast(short8, t0);                               \
    short8 pf1 = __builtin_bit_cast(short8, t1);                               \
    _Pragma("unroll")                                                          \
    for (int dt = 0; dt < 4; ++dt) {                                           \
      short8 vf0 = *(const short8*)(&Vs[P][(dt * 16 + l16) * 72 + quad * 8]);  \
      short8 vf1 = *(const short8*)(&Vs[P][(dt * 16 + l16) * 72 + 32 + quad * 8]); \
      O[dt] = __builtin_amdgcn_mfma_f32_16x16x32_bf16(pf0, vf0, O[dt], 0, 0, 0); \
      O[dt] = __builtin_amdgcn_mfma_f32_16x16x32_bf16(pf1, vf1, O[dt], 0, 0, 0); \
    }                                                                          \
  }

#define ATTN_EPI(O, LI, QT)                                                    \
  _Pragma("unroll")                                                            \
  for (int r = 0; r < 4; ++r) {                                                \
    float lv = __shfl(LI, quad * 4 + r, 16);                                   \
    float inv = 1.0f / lv;                                                     \
    int t = (QT) * 64 + wave * 16 + quad * 4 + r;                              \
    _Pragma("unroll")                                                          \
    for (int dt = 0; dt < 4; ++dt) {                                           \
      int d = dt * 16 + l16;                                                   \
      y[(((size_t)b * 2048 + t) * NH + h) * 64 + d] = (u16)f2bf(O[dt][r] * inv); \
    }                                                                          \
  }

__global__ __launch_bounds__(256, 4) void k_attn(
    const u16* __restrict__ q, const u16* __restrict__ k,
    const u16* __restrict__ vt, u16* __restrict__ y) {
  const int tid = threadIdx.x;
  const int wave = tid >> 6, lane = tid & 63;
  const int quad = lane >> 4, l16 = lane & 15;
  const int bh = blockIdx.x, bx = blockIdx.y;  // grid (64,16): id%8 = bh%8
  const int qtB = bx, qtA = 31 - bx;           // qtB in 0..15, qtA in 16..31
  const int b = bh >> 4, h = bh & 15;

  __shared__ u16 Ks[2][64 * 72];
  __shared__ u16 Vs[2][64 * 72];               // [d][kidx]

  const u16* qbA = q + ((size_t)bh * 2048 + qtA * 64 + wave * 16 + l16) * 64;
  short8 qA0 = *(const short8*)(qbA + quad * 8);
  short8 qA1 = *(const short8*)(qbA + 32 + quad * 8);
  const u16* qbB = q + ((size_t)bh * 2048 + qtB * 64 + wave * 16 + l16) * 64;
  short8 qB0 = *(const short8*)(qbB + quad * 8);
  short8 qB1 = *(const short8*)(qbB + 32 + quad * 8);

  f32x4 oA[4], oB[4];
  {
    f32x4 z = {0.f, 0.f, 0.f, 0.f};
    #pragma unroll
    for (int dt = 0; dt < 4; ++dt) { oA[dt] = z; oB[dt] = z; }
  }
  float mA = -1e30f, lA = 0.f, mB = -1e30f, lB = 0.f;

  const u16* kbase = k + (size_t)bh * 131072;
  const u16* vbase = vt + (size_t)bh * 131072;
  const int r0 = tid >> 3, cc = tid & 7;
  // P-exchange source lanes: receiver (quad,ks) pulls W[2ks+hi] words from
  // lanes s0 (j=0..3) and s1 (j=4..7)  [verified R3]
  const int s0 = ((quad & 1) << 5) + l16, s1 = s0 + 16;
  const int hi = quad >> 1;

  // prologue: stage kt=0 into buffer 0
  {
    uint4 k0 = *(const uint4*)(kbase + (size_t)r0 * 64 + cc * 8);
    uint4 k1 = *(const uint4*)(kbase + (size_t)(r0 + 32) * 64 + cc * 8);
    uint4 v0 = *(const uint4*)(vbase + (size_t)r0 * 2048 + cc * 8);
    uint4 v1 = *(const uint4*)(vbase + (size_t)(r0 + 32) * 2048 + cc * 8);
    *(uint4*)(&Ks[0][r0 * 72 + cc * 8]) = k0;
    *(uint4*)(&Ks[0][(r0 + 32) * 72 + cc * 8]) = k1;
    *(uint4*)(&Vs[0][r0 * 72 + cc * 8]) = v0;
    *(uint4*)(&Vs[0][(r0 + 32) * 72 + cc * 8]) = v1;
  }
  __syncthreads();

  for (int kt = 0; kt <= qtA; ++kt) {
    const int p = kt & 1;
    const bool pre = (kt < qtA);
    uint4 kr0, kr1, vr0, vr1;
    if (pre) {  // issue next-tile loads early; consumed after compute
      const u16* kb = kbase + (size_t)(kt + 1) * 4096;
      const u16* vb = vbase + (kt + 1) * 64;
      kr0 = *(const uint4*)(kb + (size_t)r0 * 64 + cc * 8);
      kr1 = *(const uint4*)(kb + (size_t)(r0 + 32) * 64 + cc * 8);
      vr0 = *(const uint4*)(vb + (size_t)r0 * 2048 + cc * 8);
      vr1 = *(const uint4*)(vb + (size_t)(r0 + 32) * 2048 + cc * 8);
    }

    ATTN_SUB(p, qA0, qA1, oA, mA, lA, (kt == qtA))
    if (kt <= qtB) {
      ATTN_SUB(p, qB0, qB1, oB, mB, lB, (kt == qtB))
    }

    if (pre) {  // write next tile into the other buffer
      *(uint4*)(&Ks[p ^ 1][r0 * 72 + cc * 8]) = kr0;
      *(uint4*)(&Ks[p ^ 1][(r0 + 32) * 72 + cc * 8]) = kr1;
      *(uint4*)(&Vs[p ^ 1][r0 * 72 + cc * 8]) = vr0;
      *(uint4*)(&Vs[p ^ 1][(r0 + 32) * 72 + cc * 8]) = vr1;
    }
    __syncthreads();  // single barrier: orders buf[p^1] writes + buf[p] reads
  }

  ATTN_EPI(oA, lA, qtA)
  ATTN_EPI(oB, lB, qtB)
}

extern "C" void kernel_launch(void* const* d_in, const int* in_sizes, int n_in,
                              void* d_out, int out_size, void* d_ws, size_t ws_size,
                              hipStream_t stream) {
  const float* x  = (const float*)d_in[0];
  const float* Wq = (const float*)d_in[1];
  const float* bq = (const float*)d_in[2];
  const float* Wk = (const float*)d_in[3];
  const float* bk = (const float*)d_in[4];
  const float* Wv = (const float*)d_in[5];
  const float* bv = (const float*)d_in[6];
  const float* Wo = (const float*)d_in[7];
  const float* bo = (const float*)d_in[8];
  float* out = (float*)d_out;

  u16* ws  = (u16*)d_ws;
  u16* xb  = ws;                   // 8388608   x bf16 [8192][1024]
  u16* Wb  = ws + 8388608;         // 4x1048576 Wq|Wk|Wv|Wo bf16
  u16* qkv = ws + 12582912;        // 3x8388608 q|k (v region unused now)
  u16* vt  = ws + 37748736;        // 8388608   v^T [B,H,Dh,T] bf16
  u16* y   = ws + 46137344;        // 8388608   attn out [B,T,H,Dh] bf16

  k_convert<<<dim3(12288), dim3(256), 0, stream>>>(x, Wq, Wk, Wv, Wo, ws);
  k_gemm_qkv<<<dim3(1536), dim3(512), 0, stream>>>(xb, Wb, bq, bk, bv, qkv, vt);
  k_attn<<<dim3(64, 16), dim3(256), 0, stream>>>(qkv, qkv + 8388608, vt, y);
  k_gemm_out<<<dim3(512), dim3(512), 0, stream>>>(y, Wb + 3 * 1048576, bo, out);
}